// Round 1
// baseline (865.883 us; speedup 1.0000x reference)
//
#include <hip/hip_runtime.h>
#include <hip/hip_bf16.h>

#define N_NODES 131072
#define N_EDGES 2097152
#define IN_DIM 768
#define HID 64
#define NPG 32
#define NGRAPH (N_NODES / NPG)   // 4096

#define BM 128
#define KC 64
#define LDP (KC + 8)
#define GEMM_BLOCKS (N_NODES / BM)    // 1024

// ---- radix partition geometry: ranges of 128 nodes = 4 whole graphs ----
#define RNG 128
#define NB (N_NODES / RNG)            // 1024 buckets
#define EPB 4096                      // edges per count/scatter block
#define NCB (N_EDGES / EPB)           // 512 blocks
#define PBLK 8                        // prefix stage-A blocks
#define RPB (NCB / PBLK)              // 64 rows per stage-A block
#define PREP_BLK 192                  // blocks for W transpose

typedef __attribute__((ext_vector_type(8))) short bf16x8;
typedef __attribute__((ext_vector_type(4))) float f32x4;

static __device__ __forceinline__ unsigned short f2bf(float f) {
    __hip_bfloat16 h = __float2bfloat16(f);  // hardware RNE cvt
    return *reinterpret_cast<unsigned short*>(&h);
}
static __device__ __forceinline__ float bf2f(unsigned short s) {
    return __uint_as_float(((unsigned int)s) << 16);
}

// ---- k1: W transpose (blocks < PREP_BLK) + per-block bucket histogram ----
// count path: LDS 1024-bin histogram (NO global atomics), C[cb][bkt] out.
__global__ __launch_bounds__(256) void gcn_prep_count(const float* __restrict__ W,
                                                      unsigned short* __restrict__ Wt,
                                                      const int* __restrict__ dst,
                                                      unsigned int* __restrict__ C) {
    __shared__ unsigned int hist[NB];
    int tid = threadIdx.x;
    if (blockIdx.x < PREP_BLK) {
        int i = blockIdx.x * 256 + tid;
        if (i < IN_DIM * HID) {
            int k = i >> 6, n = i & 63;
            Wt[n * IN_DIM + k] = f2bf(W[i]);
        }
        return;
    }
    int cb = blockIdx.x - PREP_BLK;
    for (int t = tid; t < NB; t += 256) hist[t] = 0u;
    __syncthreads();
    int base = cb * EPB;
    #pragma unroll
    for (int u = 0; u < EPB / 256; ++u) {
        int d = dst[base + u * 256 + tid];
        atomicAdd(&hist[d >> 7], 1u);   // shared-mem atomic only
    }
    __syncthreads();
    for (int t = tid; t < NB; t += 256) C[(size_t)cb * NB + t] = hist[t];
}

// ---- k2: bf16 GEMM h = x @ W (blocks < GEMM_BLOCKS, unchanged code)
//      + prefix stage A (8 extra blocks): in-place column prefix of C over
//      64-row groups, per-group totals to S[p][bkt]. ----
__global__ __launch_bounds__(256) void gcn_gemm_prefA(const float* __restrict__ x,
                                                      const unsigned short* __restrict__ Wt,
                                                      unsigned short* __restrict__ h,
                                                      unsigned int* __restrict__ C,
                                                      unsigned int* __restrict__ S) {
    __shared__ unsigned short xs[BM][LDP];
    int tid = threadIdx.x;

    if (blockIdx.x >= GEMM_BLOCKS) {
        int p = blockIdx.x - GEMM_BLOCKS;
        #pragma unroll
        for (int c = 0; c < 4; ++c) {
            int t = tid + c * 256;      // bucket column owned by this thread
            unsigned int run = 0;
            for (int r = 0; r < RPB; r += 8) {
                unsigned int v[8];
                size_t base = ((size_t)(p * RPB + r)) * NB + t;
                #pragma unroll
                for (int j = 0; j < 8; ++j) v[j] = C[base + (size_t)j * NB];
                #pragma unroll
                for (int j = 0; j < 8; ++j) { C[base + (size_t)j * NB] = run; run += v[j]; }
            }
            S[p * NB + t] = run;
        }
        return;
    }

    // ---- gemm path: 4 waves, tile 128x64, K chunks of 64 (verbatim from R7) ----
    int lane = tid & 63;
    int w = tid >> 6;
    int rowbase = blockIdx.x * BM;
    int r = tid >> 1, half = tid & 1;
    const float* xp = x + (size_t)(rowbase + r) * IN_DIM + half * 32;

    f32x4 acc[2][4] = {};

    for (int kb = 0; kb < IN_DIM; kb += KC) {
        __syncthreads();
        #pragma unroll
        for (int u = 0; u < 32; u += 8) {
            float4 v0 = *(const float4*)(xp + kb + u);
            float4 v1 = *(const float4*)(xp + kb + u + 4);
            bf16x8 pk;
            pk[0] = (short)f2bf(v0.x); pk[1] = (short)f2bf(v0.y);
            pk[2] = (short)f2bf(v0.z); pk[3] = (short)f2bf(v0.w);
            pk[4] = (short)f2bf(v1.x); pk[5] = (short)f2bf(v1.y);
            pk[6] = (short)f2bf(v1.z); pk[7] = (short)f2bf(v1.w);
            *(bf16x8*)&xs[r][half * 32 + u] = pk;
        }
        __syncthreads();
        #pragma unroll
        for (int ks = 0; ks < KC; ks += 32) {
            int klo = ks + (lane >> 4) * 8;
            int rl = (lane & 15);
            bf16x8 a0 = *(const bf16x8*)&xs[w * 32 + rl][klo];
            bf16x8 a1 = *(const bf16x8*)&xs[w * 32 + 16 + rl][klo];
            #pragma unroll
            for (int ct = 0; ct < 4; ++ct) {
                bf16x8 b = *(const bf16x8*)&Wt[(size_t)(ct * 16 + rl) * IN_DIM + kb + klo];
                acc[0][ct] = __builtin_amdgcn_mfma_f32_16x16x32_bf16(a0, b, acc[0][ct], 0, 0, 0);
                acc[1][ct] = __builtin_amdgcn_mfma_f32_16x16x32_bf16(a1, b, acc[1][ct], 0, 0, 0);
            }
        }
    }
    for (int rt = 0; rt < 2; ++rt) {
        int row0 = rowbase + w * 32 + rt * 16 + (lane >> 4) * 4;
        #pragma unroll
        for (int ct = 0; ct < 4; ++ct)
            #pragma unroll
            for (int rr = 0; rr < 4; ++rr) {
                int col = ct * 16 + (lane & 15);
                h[(size_t)(row0 + rr) * HID + col] = f2bf(acc[rt][ct][rr]);
            }
    }
}

// ---- k3: prefix stage B: scan S over p, then 1024-wide bucket scan ----
__global__ __launch_bounds__(1024) void gcn_prefB(unsigned int* __restrict__ S,
                                                  unsigned int* __restrict__ bstart) {
    __shared__ unsigned int sc[NB];
    int t = threadIdx.x;
    unsigned int run = 0;
    unsigned int v[PBLK];
    #pragma unroll
    for (int p = 0; p < PBLK; ++p) v[p] = S[p * NB + t];
    #pragma unroll
    for (int p = 0; p < PBLK; ++p) { S[p * NB + t] = run; run += v[p]; }
    sc[t] = run;
    __syncthreads();
    for (int off = 1; off < NB; off <<= 1) {
        unsigned int u = (t >= off) ? sc[t - off] : 0u;
        __syncthreads();
        sc[t] += u;
        __syncthreads();
    }
    bstart[t] = sc[t] - run;                 // exclusive
    if (t == NB - 1) bstart[NB] = sc[NB - 1]; // == N_EDGES
}

// ---- k4: scatter edges into bucket-contiguous order, LDS ticketing only ----
// part[pos] = src | (dst&127)<<17   (17+7 bits, fits u32)
__global__ __launch_bounds__(256) void gcn_scatter(const int* __restrict__ src,
                                                   const int* __restrict__ dst,
                                                   const unsigned int* __restrict__ C,
                                                   const unsigned int* __restrict__ S,
                                                   const unsigned int* __restrict__ bstart,
                                                   unsigned int* __restrict__ part) {
    __shared__ unsigned int off[NB];
    int tid = threadIdx.x, cb = blockIdx.x;
    int p = cb >> 6;  // cb / RPB
    for (int t = tid; t < NB; t += 256)
        off[t] = bstart[t] + S[p * NB + t] + C[(size_t)cb * NB + t];
    __syncthreads();
    int base = cb * EPB;
    #pragma unroll
    for (int u = 0; u < EPB / 256; ++u) {
        int i = base + u * 256 + tid;
        int d = dst[i];
        unsigned int pos = atomicAdd(&off[d >> 7], 1u);
        part[pos] = (unsigned int)src[i] | ((unsigned int)(d & (RNG - 1)) << 17);
    }
}

// ---- k5: per-node degree -> dinv (LDS bins, coalesced reads/writes) ----
__global__ __launch_bounds__(256) void gcn_deg(const unsigned int* __restrict__ part,
                                               const unsigned int* __restrict__ bstart,
                                               float* __restrict__ dinv) {
    __shared__ unsigned int bin[RNG];
    int tid = threadIdx.x, b = blockIdx.x;
    if (tid < RNG) bin[tid] = 0u;
    __syncthreads();
    unsigned int s0 = bstart[b], s1 = bstart[b + 1];
    for (unsigned int j = s0 + tid; j < s1; j += 256)
        atomicAdd(&bin[part[j] >> 17], 1u);
    __syncthreads();
    if (tid < RNG) dinv[b * RNG + tid] = rsqrtf((float)(bin[tid] + 1));
}

// ---- k6: range-local aggregation + relu + W_lin + per-graph logsoftmax ----
// Block b owns nodes [b*128, b*128+128) = graphs 4b..4b+3. LDS f32 acc tile.
#define LDA 65   // +1 pad: varies row start bank, keeps epilogue conflict-free
__global__ __launch_bounds__(256) void gcn_agg(const unsigned short* __restrict__ h,
                                               const unsigned int* __restrict__ part,
                                               const unsigned int* __restrict__ bstart,
                                               const float* __restrict__ dinv,
                                               const float* __restrict__ b_conv,
                                               const float* __restrict__ W_lin,
                                               const float* __restrict__ b_lin,
                                               float* __restrict__ out) {
    __shared__ float acc[RNG][LDA];   // 33.3 KB -> 4 blocks/CU
    int tid = threadIdx.x, lane = tid & 63, w = tid >> 6;
    int b = blockIdx.x;

    for (int t = tid; t < RNG * LDA; t += 256) ((float*)acc)[t] = 0.f;
    __syncthreads();

    unsigned int s0 = bstart[b], s1 = bstart[b + 1];
    unsigned int cntE = s1 - s0;
    unsigned int chunk = (cntE + 3) >> 2;
    unsigned int ws_ = s0 + (unsigned int)w * chunk;
    if (ws_ > s1) ws_ = s1;
    unsigned int we_ = ws_ + chunk;
    if (we_ > s1) we_ = s1;

    int q = lane >> 5, ln = lane & 31;   // half-wave per edge, 2 dims per lane
    unsigned int e = ws_;
    for (; e + 8 <= we_; e += 8) {
        unsigned int pr0 = part[e + 0 + q];
        unsigned int pr1 = part[e + 2 + q];
        unsigned int pr2 = part[e + 4 + q];
        unsigned int pr3 = part[e + 6 + q];
        int si0 = pr0 & 0x1FFFF, dl0 = pr0 >> 17;
        int si1 = pr1 & 0x1FFFF, dl1 = pr1 >> 17;
        int si2 = pr2 & 0x1FFFF, dl2 = pr2 >> 17;
        int si3 = pr3 & 0x1FFFF, dl3 = pr3 >> 17;
        float n0 = dinv[si0], n1 = dinv[si1], n2 = dinv[si2], n3 = dinv[si3];
        unsigned int h0 = *(const unsigned int*)(h + (size_t)si0 * HID + ln * 2);
        unsigned int h1 = *(const unsigned int*)(h + (size_t)si1 * HID + ln * 2);
        unsigned int h2 = *(const unsigned int*)(h + (size_t)si2 * HID + ln * 2);
        unsigned int h3 = *(const unsigned int*)(h + (size_t)si3 * HID + ln * 2);
        atomicAdd(&acc[dl0][ln * 2 + 0], bf2f((unsigned short)(h0 & 0xffff)) * n0);
        atomicAdd(&acc[dl0][ln * 2 + 1], bf2f((unsigned short)(h0 >> 16)) * n0);
        atomicAdd(&acc[dl1][ln * 2 + 0], bf2f((unsigned short)(h1 & 0xffff)) * n1);
        atomicAdd(&acc[dl1][ln * 2 + 1], bf2f((unsigned short)(h1 >> 16)) * n1);
        atomicAdd(&acc[dl2][ln * 2 + 0], bf2f((unsigned short)(h2 & 0xffff)) * n2);
        atomicAdd(&acc[dl2][ln * 2 + 1], bf2f((unsigned short)(h2 >> 16)) * n2);
        atomicAdd(&acc[dl3][ln * 2 + 0], bf2f((unsigned short)(h3 & 0xffff)) * n3);
        atomicAdd(&acc[dl3][ln * 2 + 1], bf2f((unsigned short)(h3 >> 16)) * n3);
    }
    for (; e < we_; e += 2) {
        unsigned int idx = e + q;
        if (idx < we_) {
            unsigned int pr = part[idx];
            int si = pr & 0x1FFFF, dl = pr >> 17;
            float n = dinv[si];
            unsigned int hv = *(const unsigned int*)(h + (size_t)si * HID + ln * 2);
            atomicAdd(&acc[dl][ln * 2 + 0], bf2f((unsigned short)(hv & 0xffff)) * n);
            atomicAdd(&acc[dl][ln * 2 + 1], bf2f((unsigned short)(hv >> 16)) * n);
        }
    }
    __syncthreads();

    // epilogue: wave w -> graph g = 4b+w (32 nodes), full logits + logsoftmax
    int g = b * 4 + w;
    int nbase = b * RNG + w * 32;
    float bc = b_conv[lane];
    float l0 = 0.f, l1 = 0.f;
    for (int k = 0; k < 32; ++k) {
        int i = nbase + k;
        float di = dinv[i];
        float a = acc[w * 32 + k][lane];
        float hs = bf2f(h[(size_t)i * HID + lane]);
        float ttl = fmaf(di, hs, a);                  // sum_s ds*h_s + di*h_i
        float v = fmaxf(fmaf(ttl, di, bc), 0.f);
        l0 = fmaf(v, W_lin[k * HID + lane], l0);
        l1 = fmaf(v, W_lin[HID * NPG + k * HID + lane], l1);
    }
    #pragma unroll
    for (int d2 = 32; d2 > 0; d2 >>= 1) {
        l0 += __shfl_down(l0, d2);
        l1 += __shfl_down(l1, d2);
    }
    if (lane == 0) {
        float A = l0 + b_lin[0];
        float B = l1 + b_lin[1];
        float m = fmaxf(A, B);
        float lse = m + logf(expf(A - m) + expf(B - m));
        out[g * 2 + 0] = A - lse;
        out[g * 2 + 1] = B - lse;
    }
}

extern "C" void kernel_launch(void* const* d_in, const int* in_sizes, int n_in,
                              void* d_out, int out_size, void* d_ws, size_t ws_size,
                              hipStream_t stream) {
    const float* x  = (const float*)d_in[0];
    const int* ei   = (const int*)d_in[1];
    const float* Wc = (const float*)d_in[2];
    const float* bc = (const float*)d_in[3];
    const float* Wl = (const float*)d_in[4];
    const float* bl = (const float*)d_in[5];
    float* out = (float*)d_out;

    char* ws = (char*)d_ws;
    unsigned short* Wt   = (unsigned short*)(ws);                 // 96 KB
    float*          dinv = (float*)(ws + (128 << 10));            // 512 KB
    unsigned int*  bstart= (unsigned int*)(ws + (640 << 10));     // 4.1 KB
    unsigned int*  S     = (unsigned int*)(ws + (656 << 10));     // 32 KB
    unsigned int*  C     = (unsigned int*)(ws + (1024 << 10));    // 2 MB
    unsigned int*  part  = (unsigned int*)(ws + (3u << 20));      // 8 MB
    unsigned short* h    = (unsigned short*)(ws + (11u << 20));   // 16 MB
    // total 27 MB < previous proven 44.5 MB footprint

    const int* srcIdx = ei;
    const int* dstIdx = ei + N_EDGES;

    gcn_prep_count<<<PREP_BLK + NCB, 256, 0, stream>>>(Wc, Wt, dstIdx, C);
    gcn_gemm_prefA<<<GEMM_BLOCKS + PBLK, 256, 0, stream>>>(x, Wt, h, C, S);
    gcn_prefB<<<1, 1024, 0, stream>>>(S, bstart);
    gcn_scatter<<<NCB, 256, 0, stream>>>(srcIdx, dstIdx, C, S, bstart, part);
    gcn_deg<<<NB, 256, 0, stream>>>(part, bstart, dinv);
    gcn_agg<<<NB, 256, 0, stream>>>(h, part, bstart, dinv, bc, Wl, bl, out);
}